// Round 1
// baseline (2231.160 us; speedup 1.0000x reference)
//
#include <hip/hip_runtime.h>
#include <hip/hip_bf16.h>
#include <cstdint>

// ---------------------------------------------------------------------------
// LlamaMlpWithLora: T=2048, H=4096, I=11008, A=8, L=1, R=16, scale=0.5
// Strategy: bf16 MFMA GEMMs (m97 128x128 structure), fused LoRA epilogues.
// ---------------------------------------------------------------------------

#define T_TOK 2048
#define H_DIM 4096
#define I_DIM 11008
#define R_LORA 16

typedef __bf16 bf16x8 __attribute__((ext_vector_type(8)));
typedef float f32x4 __attribute__((ext_vector_type(4)));

__device__ __forceinline__ float bf2f(unsigned short u) {
    union { unsigned int i; float f; } v;
    v.i = ((unsigned int)u) << 16;
    return v.f;
}
__device__ __forceinline__ unsigned short f2bf(float f) {
    __bf16 b = (__bf16)f;
    unsigned short u;
    __builtin_memcpy(&u, &b, 2);
    return u;
}

// ------------------------------ f32 -> bf16 convert ------------------------
__global__ __launch_bounds__(256) void cvt_f32_to_bf16(
    const float* __restrict__ src, unsigned short* __restrict__ dst, long long n8)
{
    long long i = (long long)blockIdx.x * blockDim.x + threadIdx.x;
    long long stride = (long long)gridDim.x * blockDim.x;
    for (; i < n8; i += stride) {
        const float4* s = reinterpret_cast<const float4*>(src + i * 8);
        float4 a = s[0];
        float4 b = s[1];
        uint4 o;
        o.x = (unsigned)f2bf(a.x) | ((unsigned)f2bf(a.y) << 16);
        o.y = (unsigned)f2bf(a.z) | ((unsigned)f2bf(a.w) << 16);
        o.z = (unsigned)f2bf(b.x) | ((unsigned)f2bf(b.y) << 16);
        o.w = (unsigned)f2bf(b.z) | ((unsigned)f2bf(b.w) << 16);
        *reinterpret_cast<uint4*>(dst + i * 8) = o;
    }
}

// ------------------------------ LoRA v = x . waT ---------------------------
// v_gate/v_up: [T,16] fp32, from fp32 x (accurate), wa: [A,1,16,H]
__global__ __launch_bounds__(256) void lora_v_gu(
    const float* __restrict__ x, const float* __restrict__ gwa,
    const float* __restrict__ uwa, const int* __restrict__ idx,
    float* __restrict__ vg, float* __restrict__ vu)
{
    const int t = blockIdx.x;
    const int a = idx[t];
    const int wid = threadIdx.x >> 6;
    const int lane = threadIdx.x & 63;
    const float* xr = x + (size_t)t * H_DIM;
    const float* wa = (wid < 2 ? gwa : uwa) + (size_t)a * R_LORA * H_DIM;
    float* vout = (wid < 2 ? vg : vu) + t * R_LORA;
    const int r0 = (wid & 1) * 8;
    for (int r = r0; r < r0 + 8; ++r) {
        const float* w = wa + (size_t)r * H_DIM;
        float s = 0.f;
        for (int h = lane; h < H_DIM; h += 64) s += xr[h] * w[h];
        #pragma unroll
        for (int off = 32; off > 0; off >>= 1) s += __shfl_down(s, off);
        if (lane == 0) vout[r] = s;
    }
}

// v_down: [T,16] fp32 from bf16 t, wa: [A,1,16,I]
__global__ __launch_bounds__(256) void lora_v_down_k(
    const unsigned short* __restrict__ tmat, const float* __restrict__ dwa,
    const int* __restrict__ idx, float* __restrict__ vd)
{
    const int tok = blockIdx.x;
    const int a = idx[tok];
    const int wid = threadIdx.x >> 6;
    const int lane = threadIdx.x & 63;
    const unsigned short* tr = tmat + (size_t)tok * I_DIM;
    const float* wa = dwa + (size_t)a * R_LORA * I_DIM;
    #pragma unroll
    for (int rr = 0; rr < 4; ++rr) {
        const int r = wid * 4 + rr;
        const float* w = wa + (size_t)r * I_DIM;
        float s = 0.f;
        for (int h = lane; h < I_DIM; h += 64) s += bf2f(tr[h]) * w[h];
        #pragma unroll
        for (int off = 32; off > 0; off >>= 1) s += __shfl_down(s, off);
        if (lane == 0) vd[tok * R_LORA + r] = s;
    }
}

// ------------------------------ GEMM C = A * B^T ---------------------------
// A: [M,K] bf16 row-major, B: [N,K] bf16 row-major. 128x128 tile, BK=64.
// 256 threads = 4 waves (2x2), each wave 64x64 via 4x4 frags of 16x16x32.
// MODE 0: out_bf16 = raw acc (gate)
// MODE 1: t = silu(gate_in + 0.5*vg.wbg) * (acc + 0.5*vu.wbu)  -> out_bf16
// MODE 2: out_f32 = acc + 0.5*vd.wbd
__device__ __forceinline__ void gload_lds16(const void* g, void* l) {
    __builtin_amdgcn_global_load_lds(
        (const __attribute__((address_space(1))) void*)g,
        (__attribute__((address_space(3))) void*)l,
        16, 0, 0);
}

template <int MODE>
__global__ __launch_bounds__(256) void gemm_bt(
    const unsigned short* __restrict__ A, const unsigned short* __restrict__ B,
    int M, int N, int K,
    unsigned short* __restrict__ out_bf16,
    const unsigned short* __restrict__ gate_in,
    float* __restrict__ out_f32,
    const float* __restrict__ v1, const float* __restrict__ v2,
    const float* __restrict__ wb1, const float* __restrict__ wb2,
    const int* __restrict__ idx)
{
    (void)M;
    __shared__ __align__(16) unsigned short As[128][64];
    __shared__ __align__(16) unsigned short Bs[128][64];

    const int tid = threadIdx.x;
    const int lane = tid & 63;
    const int wid = tid >> 6;
    const int wr = wid >> 1;
    const int wc = wid & 1;
    const int fr = lane & 15;
    const int fo = (lane >> 4) * 8;

    const int bn0 = blockIdx.x * 128;
    const int bm0 = blockIdx.y * 128;

    // staging map: thread tid -> row (tid>>3), col ((tid&7)*8); 4 iters of +32 rows
    const int srow = tid >> 3;
    const int scol = (tid & 7) * 8;
    const unsigned short* gA = A + (size_t)(bm0 + srow) * K + scol;
    const unsigned short* gB = B + (size_t)(bn0 + srow) * K + scol;
    unsigned short* lA = &As[srow][scol];
    unsigned short* lB = &Bs[srow][scol];

    f32x4 acc[4][4] = {};

    for (int kt = 0; kt < K; kt += 64) {
        #pragma unroll
        for (int it = 0; it < 4; ++it) {
            gload_lds16(gA + (size_t)(it * 32) * K + kt, lA + it * 32 * 64);
            gload_lds16(gB + (size_t)(it * 32) * K + kt, lB + it * 32 * 64);
        }
        __syncthreads();
        #pragma unroll
        for (int kk = 0; kk < 64; kk += 32) {
            bf16x8 af[4];
            bf16x8 bfv[4];
            #pragma unroll
            for (int m = 0; m < 4; ++m)
                af[m] = *reinterpret_cast<const bf16x8*>(&As[wr * 64 + m * 16 + fr][kk + fo]);
            #pragma unroll
            for (int n = 0; n < 4; ++n)
                bfv[n] = *reinterpret_cast<const bf16x8*>(&Bs[wc * 64 + n * 16 + fr][kk + fo]);
            #pragma unroll
            for (int m = 0; m < 4; ++m)
                #pragma unroll
                for (int n = 0; n < 4; ++n)
                    acc[m][n] = __builtin_amdgcn_mfma_f32_16x16x32_bf16(
                        af[m], bfv[n], acc[m][n], 0, 0, 0);
        }
        __syncthreads();
    }

    // C/D layout (verified m89/m91): col = lane&15, row = (lane>>4)*4 + reg
    const int orow0 = bm0 + wr * 64 + (lane >> 4) * 4;
    const int ocol0 = bn0 + wc * 64 + fr;

    if constexpr (MODE == 0) {
        #pragma unroll
        for (int m = 0; m < 4; ++m)
            #pragma unroll
            for (int j = 0; j < 4; ++j) {
                const int row = orow0 + m * 16 + j;
                #pragma unroll
                for (int n = 0; n < 4; ++n)
                    out_bf16[(size_t)row * N + ocol0 + n * 16] = f2bf(acc[m][n][j]);
            }
    } else if constexpr (MODE == 1) {
        #pragma unroll
        for (int m = 0; m < 4; ++m) {
            #pragma unroll
            for (int j = 0; j < 4; ++j) {
                const int row = orow0 + m * 16 + j;
                const int a = idx[row];
                const float* vg = v1 + row * R_LORA;
                const float* vu = v2 + row * R_LORA;
                #pragma unroll
                for (int n = 0; n < 4; ++n) {
                    const int col = ocol0 + n * 16;
                    const float* wg = wb1 + ((size_t)a * N + col) * R_LORA;
                    const float* wu = wb2 + ((size_t)a * N + col) * R_LORA;
                    float lg = 0.f, lu = 0.f;
                    #pragma unroll
                    for (int r = 0; r < R_LORA; ++r) {
                        lg += vg[r] * wg[r];
                        lu += vu[r] * wu[r];
                    }
                    float g = bf2f(gate_in[(size_t)row * N + col]) + 0.5f * lg;
                    float u = acc[m][n][j] + 0.5f * lu;
                    float sg = g / (1.f + __expf(-g));
                    out_bf16[(size_t)row * N + col] = f2bf(sg * u);
                }
            }
        }
    } else {
        #pragma unroll
        for (int m = 0; m < 4; ++m) {
            #pragma unroll
            for (int j = 0; j < 4; ++j) {
                const int row = orow0 + m * 16 + j;
                const int a = idx[row];
                const float* vd = v1 + row * R_LORA;
                #pragma unroll
                for (int n = 0; n < 4; ++n) {
                    const int col = ocol0 + n * 16;
                    const float* wd = wb1 + ((size_t)a * N + col) * R_LORA;
                    float ld = 0.f;
                    #pragma unroll
                    for (int r = 0; r < R_LORA; ++r) ld += vd[r] * wd[r];
                    out_f32[(size_t)row * N + col] = acc[m][n][j] + 0.5f * ld;
                }
            }
        }
    }
}

// ---------------------------------------------------------------------------
extern "C" void kernel_launch(void* const* d_in, const int* in_sizes, int n_in,
                              void* d_out, int out_size, void* d_ws, size_t ws_size,
                              hipStream_t stream)
{
    const float* x       = (const float*)d_in[0];
    const float* gate_w  = (const float*)d_in[1];
    const float* up_w    = (const float*)d_in[2];
    const float* down_w  = (const float*)d_in[3];
    const float* gate_wa = (const float*)d_in[4];
    const float* gate_wb = (const float*)d_in[5];
    const float* up_wa   = (const float*)d_in[6];
    const float* up_wb   = (const float*)d_in[7];
    const float* down_wa = (const float*)d_in[8];
    const float* down_wb = (const float*)d_in[9];
    const int*   indices = (const int*)d_in[10];
    float* out = (float*)d_out;

    char* ws = (char*)d_ws;
    size_t off = 0;
    auto alloc = [&](size_t bytes) {
        char* p = ws + off;
        off += (bytes + 255) & ~(size_t)255;
        return p;
    };
    const size_t W_BYTES = (size_t)I_DIM * H_DIM * 2;          // 90.2 MB (reused slot)
    unsigned short* w1    = (unsigned short*)alloc(W_BYTES);
    unsigned short* xb    = (unsigned short*)alloc((size_t)T_TOK * H_DIM * 2);
    unsigned short* gateB = (unsigned short*)alloc((size_t)T_TOK * I_DIM * 2);
    unsigned short* tB    = (unsigned short*)alloc((size_t)T_TOK * I_DIM * 2);
    float* v_gate = (float*)alloc((size_t)T_TOK * R_LORA * 4);
    float* v_up   = (float*)alloc((size_t)T_TOK * R_LORA * 4);
    float* v_down = (float*)alloc((size_t)T_TOK * R_LORA * 4);

    const long long n8_x = (long long)T_TOK * H_DIM / 8;
    const long long n8_w = (long long)I_DIM * H_DIM / 8;

    // x -> bf16; gate_w -> bf16
    cvt_f32_to_bf16<<<2048, 256, 0, stream>>>(x, xb, n8_x);
    cvt_f32_to_bf16<<<4096, 256, 0, stream>>>(gate_w, w1, n8_w);
    // LoRA v for gate/up (from fp32 x)
    lora_v_gu<<<T_TOK, 256, 0, stream>>>(x, gate_wa, up_wa, indices, v_gate, v_up);

    // gate = x @ gate_w^T  (raw, bf16)
    gemm_bt<0><<<dim3(I_DIM / 128, T_TOK / 128), 256, 0, stream>>>(
        xb, w1, T_TOK, I_DIM, H_DIM, gateB, nullptr, nullptr,
        nullptr, nullptr, nullptr, nullptr, indices);

    // up_w -> bf16 (reuse slot), then fused up-GEMM -> t
    cvt_f32_to_bf16<<<4096, 256, 0, stream>>>(up_w, w1, n8_w);
    gemm_bt<1><<<dim3(I_DIM / 128, T_TOK / 128), 256, 0, stream>>>(
        xb, w1, T_TOK, I_DIM, H_DIM, tB, gateB, nullptr,
        v_gate, v_up, gate_wb, up_wb, indices);

    // down_w -> bf16 (reuse slot), v_down from t, down-GEMM -> out (fp32)
    cvt_f32_to_bf16<<<4096, 256, 0, stream>>>(down_w, w1, n8_w);
    lora_v_down_k<<<T_TOK, 256, 0, stream>>>(tB, down_wa, indices, v_down);
    gemm_bt<2><<<dim3(H_DIM / 128, T_TOK / 128), 256, 0, stream>>>(
        tB, w1, T_TOK, H_DIM, I_DIM, nullptr, nullptr, out,
        v_down, nullptr, down_wb, nullptr, indices);

    (void)in_sizes; (void)n_in; (void)out_size; (void)ws_size;
}

// Round 2
// 2059.422 us; speedup vs baseline: 1.0834x; 1.0834x over previous
//
#include <hip/hip_runtime.h>
#include <hip/hip_bf16.h>
#include <cstdint>

// ---------------------------------------------------------------------------
// LlamaMlpWithLora: T=2048, H=4096, I=11008, A=8, L=1, R=16, scale=0.5
// bf16 MFMA GEMMs (128x128 tile, BK=64) + T2 LDS XOR-swizzle:
//   physical 16B-slot = logical slot ^ (row&7), applied on BOTH sides:
//   - staging: linear LDS dest (global_load_lds requirement) + inverse-
//     swizzled per-lane GLOBAL source column (m173 pattern)
//   - fragment ds_read_b128: swizzled slot
// Fused LoRA epilogues (silu(gate+lora)*(up+lora), down+lora).
// ---------------------------------------------------------------------------

#define T_TOK 2048
#define H_DIM 4096
#define I_DIM 11008
#define R_LORA 16

typedef __bf16 bf16x8 __attribute__((ext_vector_type(8)));
typedef float f32x4 __attribute__((ext_vector_type(4)));

__device__ __forceinline__ float bf2f(unsigned short u) {
    union { unsigned int i; float f; } v;
    v.i = ((unsigned int)u) << 16;
    return v.f;
}
__device__ __forceinline__ unsigned short f2bf(float f) {
    __bf16 b = (__bf16)f;
    unsigned short u;
    __builtin_memcpy(&u, &b, 2);
    return u;
}

// ------------------------------ f32 -> bf16 convert ------------------------
__global__ __launch_bounds__(256) void cvt_f32_to_bf16(
    const float* __restrict__ src, unsigned short* __restrict__ dst, long long n8)
{
    long long i = (long long)blockIdx.x * blockDim.x + threadIdx.x;
    long long stride = (long long)gridDim.x * blockDim.x;
    for (; i < n8; i += stride) {
        const float4* s = reinterpret_cast<const float4*>(src + i * 8);
        float4 a = s[0];
        float4 b = s[1];
        uint4 o;
        o.x = (unsigned)f2bf(a.x) | ((unsigned)f2bf(a.y) << 16);
        o.y = (unsigned)f2bf(a.z) | ((unsigned)f2bf(a.w) << 16);
        o.z = (unsigned)f2bf(b.x) | ((unsigned)f2bf(b.y) << 16);
        o.w = (unsigned)f2bf(b.z) | ((unsigned)f2bf(b.w) << 16);
        *reinterpret_cast<uint4*>(dst + i * 8) = o;
    }
}

// ------------------------------ LoRA v = x . waT ---------------------------
__global__ __launch_bounds__(256) void lora_v_gu(
    const float* __restrict__ x, const float* __restrict__ gwa,
    const float* __restrict__ uwa, const int* __restrict__ idx,
    float* __restrict__ vg, float* __restrict__ vu)
{
    const int t = blockIdx.x;
    const int a = idx[t];
    const int wid = threadIdx.x >> 6;
    const int lane = threadIdx.x & 63;
    const float* xr = x + (size_t)t * H_DIM;
    const float* wa = (wid < 2 ? gwa : uwa) + (size_t)a * R_LORA * H_DIM;
    float* vout = (wid < 2 ? vg : vu) + t * R_LORA;
    const int r0 = (wid & 1) * 8;
    for (int r = r0; r < r0 + 8; ++r) {
        const float* w = wa + (size_t)r * H_DIM;
        float s = 0.f;
        for (int h = lane; h < H_DIM; h += 64) s += xr[h] * w[h];
        #pragma unroll
        for (int off = 32; off > 0; off >>= 1) s += __shfl_down(s, off);
        if (lane == 0) vout[r] = s;
    }
}

__global__ __launch_bounds__(256) void lora_v_down_k(
    const unsigned short* __restrict__ tmat, const float* __restrict__ dwa,
    const int* __restrict__ idx, float* __restrict__ vd)
{
    const int tok = blockIdx.x;
    const int a = idx[tok];
    const int wid = threadIdx.x >> 6;
    const int lane = threadIdx.x & 63;
    const unsigned short* tr = tmat + (size_t)tok * I_DIM;
    const float* wa = dwa + (size_t)a * R_LORA * I_DIM;
    #pragma unroll
    for (int rr = 0; rr < 4; ++rr) {
        const int r = wid * 4 + rr;
        const float* w = wa + (size_t)r * I_DIM;
        float s = 0.f;
        for (int h = lane; h < I_DIM; h += 64) s += bf2f(tr[h]) * w[h];
        #pragma unroll
        for (int off = 32; off > 0; off >>= 1) s += __shfl_down(s, off);
        if (lane == 0) vd[tok * R_LORA + r] = s;
    }
}

// ------------------------------ GEMM C = A * B^T ---------------------------
__device__ __forceinline__ void gload_lds16(const void* g, void* l) {
    __builtin_amdgcn_global_load_lds(
        (const __attribute__((address_space(1))) void*)g,
        (__attribute__((address_space(3))) void*)l,
        16, 0, 0);
}

template <int MODE>
__global__ __launch_bounds__(256) void gemm_bt(
    const unsigned short* __restrict__ A, const unsigned short* __restrict__ B,
    int M, int N, int K,
    unsigned short* __restrict__ out_bf16,
    const unsigned short* __restrict__ gate_in,
    float* __restrict__ out_f32,
    const float* __restrict__ v1, const float* __restrict__ v2,
    const float* __restrict__ wb1, const float* __restrict__ wb2,
    const int* __restrict__ idx)
{
    (void)M;
    __shared__ __align__(16) unsigned short As[128][64];
    __shared__ __align__(16) unsigned short Bs[128][64];

    const int tid = threadIdx.x;
    const int lane = tid & 63;
    const int wid = tid >> 6;
    const int wr = wid >> 1;
    const int wc = wid & 1;
    const int fr = lane & 15;       // fragment row within 16
    const int hi = lane >> 4;       // 0..3 -> logical 16B slot offset
    const int fsw = fr & 7;         // row-derived swizzle key

    const int bn0 = blockIdx.x * 128;
    const int bm0 = blockIdx.y * 128;

    // Staging: thread tid covers LDS byte offset tid*16 (linear, per
    // global_load_lds's wave-uniform-base + lane*16 rule). Physical slot p
    // at row r holds logical slot p ^ (r&7), so the GLOBAL source column is
    // pre-swizzled with the same involution.
    const int srow = tid >> 3;
    const int sslot = tid & 7;
    const int gcol = ((sslot ^ (srow & 7)) * 8);
    const unsigned short* gA = A + (size_t)(bm0 + srow) * K + gcol;
    const unsigned short* gB = B + (size_t)(bn0 + srow) * K + gcol;
    unsigned short* lA = &As[srow][sslot * 8];
    unsigned short* lB = &Bs[srow][sslot * 8];

    f32x4 acc[4][4] = {};

    for (int kt = 0; kt < K; kt += 64) {
        #pragma unroll
        for (int it = 0; it < 4; ++it) {
            gload_lds16(gA + (size_t)(it * 32) * K + kt, lA + it * 32 * 64);
            gload_lds16(gB + (size_t)(it * 32) * K + kt, lB + it * 32 * 64);
        }
        __syncthreads();
        #pragma unroll
        for (int kk = 0; kk < 64; kk += 32) {
            const int ls = kk >> 3;   // logical slot base (0 or 4)
            bf16x8 af[4];
            bf16x8 bfv[4];
            #pragma unroll
            for (int m = 0; m < 4; ++m)
                af[m] = *reinterpret_cast<const bf16x8*>(
                    &As[wr * 64 + m * 16 + fr][((ls + hi) ^ fsw) * 8]);
            #pragma unroll
            for (int n = 0; n < 4; ++n)
                bfv[n] = *reinterpret_cast<const bf16x8*>(
                    &Bs[wc * 64 + n * 16 + fr][((ls + hi) ^ fsw) * 8]);
            #pragma unroll
            for (int m = 0; m < 4; ++m)
                #pragma unroll
                for (int n = 0; n < 4; ++n)
                    acc[m][n] = __builtin_amdgcn_mfma_f32_16x16x32_bf16(
                        af[m], bfv[n], acc[m][n], 0, 0, 0);
        }
        __syncthreads();
    }

    // C/D layout (verified m89/m91): col = lane&15, row = (lane>>4)*4 + reg
    const int orow0 = bm0 + wr * 64 + (lane >> 4) * 4;
    const int ocol0 = bn0 + wc * 64 + fr;

    if constexpr (MODE == 0) {
        #pragma unroll
        for (int m = 0; m < 4; ++m)
            #pragma unroll
            for (int j = 0; j < 4; ++j) {
                const int row = orow0 + m * 16 + j;
                #pragma unroll
                for (int n = 0; n < 4; ++n)
                    out_bf16[(size_t)row * N + ocol0 + n * 16] = f2bf(acc[m][n][j]);
            }
    } else if constexpr (MODE == 1) {
        #pragma unroll
        for (int m = 0; m < 4; ++m) {
            #pragma unroll
            for (int j = 0; j < 4; ++j) {
                const int row = orow0 + m * 16 + j;
                const int a = idx[row];
                const float* vg = v1 + row * R_LORA;
                const float* vu = v2 + row * R_LORA;
                #pragma unroll
                for (int n = 0; n < 4; ++n) {
                    const int col = ocol0 + n * 16;
                    const float* wg = wb1 + ((size_t)a * N + col) * R_LORA;
                    const float* wu = wb2 + ((size_t)a * N + col) * R_LORA;
                    float lg = 0.f, lu = 0.f;
                    #pragma unroll
                    for (int r = 0; r < R_LORA; ++r) {
                        lg += vg[r] * wg[r];
                        lu += vu[r] * wu[r];
                    }
                    float g = bf2f(gate_in[(size_t)row * N + col]) + 0.5f * lg;
                    float u = acc[m][n][j] + 0.5f * lu;
                    float sg = g / (1.f + __expf(-g));
                    out_bf16[(size_t)row * N + col] = f2bf(sg * u);
                }
            }
        }
    } else {
        #pragma unroll
        for (int m = 0; m < 4; ++m) {
            #pragma unroll
            for (int j = 0; j < 4; ++j) {
                const int row = orow0 + m * 16 + j;
                const int a = idx[row];
                const float* vd = v1 + row * R_LORA;
                #pragma unroll
                for (int n = 0; n < 4; ++n) {
                    const int col = ocol0 + n * 16;
                    const float* wd = wb1 + ((size_t)a * N + col) * R_LORA;
                    float ld = 0.f;
                    #pragma unroll
                    for (int r = 0; r < R_LORA; ++r) ld += vd[r] * wd[r];
                    out_f32[(size_t)row * N + col] = acc[m][n][j] + 0.5f * ld;
                }
            }
        }
    }
}

// ---------------------------------------------------------------------------
extern "C" void kernel_launch(void* const* d_in, const int* in_sizes, int n_in,
                              void* d_out, int out_size, void* d_ws, size_t ws_size,
                              hipStream_t stream)
{
    const float* x       = (const float*)d_in[0];
    const float* gate_w  = (const float*)d_in[1];
    const float* up_w    = (const float*)d_in[2];
    const float* down_w  = (const float*)d_in[3];
    const float* gate_wa = (const float*)d_in[4];
    const float* gate_wb = (const float*)d_in[5];
    const float* up_wa   = (const float*)d_in[6];
    const float* up_wb   = (const float*)d_in[7];
    const float* down_wa = (const float*)d_in[8];
    const float* down_wb = (const float*)d_in[9];
    const int*   indices = (const int*)d_in[10];
    float* out = (float*)d_out;

    char* ws = (char*)d_ws;
    size_t off = 0;
    auto alloc = [&](size_t bytes) {
        char* p = ws + off;
        off += (bytes + 255) & ~(size_t)255;
        return p;
    };
    const size_t W_BYTES = (size_t)I_DIM * H_DIM * 2;          // 90.2 MB (reused slot)
    unsigned short* w1    = (unsigned short*)alloc(W_BYTES);
    unsigned short* xb    = (unsigned short*)alloc((size_t)T_TOK * H_DIM * 2);
    unsigned short* gateB = (unsigned short*)alloc((size_t)T_TOK * I_DIM * 2);
    unsigned short* tB    = (unsigned short*)alloc((size_t)T_TOK * I_DIM * 2);
    float* v_gate = (float*)alloc((size_t)T_TOK * R_LORA * 4);
    float* v_up   = (float*)alloc((size_t)T_TOK * R_LORA * 4);
    float* v_down = (float*)alloc((size_t)T_TOK * R_LORA * 4);

    const long long n8_x = (long long)T_TOK * H_DIM / 8;
    const long long n8_w = (long long)I_DIM * H_DIM / 8;

    cvt_f32_to_bf16<<<2048, 256, 0, stream>>>(x, xb, n8_x);
    cvt_f32_to_bf16<<<4096, 256, 0, stream>>>(gate_w, w1, n8_w);
    lora_v_gu<<<T_TOK, 256, 0, stream>>>(x, gate_wa, up_wa, indices, v_gate, v_up);

    // gate = x @ gate_w^T  (raw, bf16)
    gemm_bt<0><<<dim3(I_DIM / 128, T_TOK / 128), 256, 0, stream>>>(
        xb, w1, T_TOK, I_DIM, H_DIM, gateB, nullptr, nullptr,
        nullptr, nullptr, nullptr, nullptr, indices);

    // up_w -> bf16 (reuse slot), fused up-GEMM -> t
    cvt_f32_to_bf16<<<4096, 256, 0, stream>>>(up_w, w1, n8_w);
    gemm_bt<1><<<dim3(I_DIM / 128, T_TOK / 128), 256, 0, stream>>>(
        xb, w1, T_TOK, I_DIM, H_DIM, tB, gateB, nullptr,
        v_gate, v_up, gate_wb, up_wb, indices);

    // down_w -> bf16 (reuse slot), v_down from t, down-GEMM -> out (fp32)
    cvt_f32_to_bf16<<<4096, 256, 0, stream>>>(down_w, w1, n8_w);
    lora_v_down_k<<<T_TOK, 256, 0, stream>>>(tB, down_wa, indices, v_down);
    gemm_bt<2><<<dim3(H_DIM / 128, T_TOK / 128), 256, 0, stream>>>(
        tB, w1, T_TOK, H_DIM, I_DIM, nullptr, nullptr, out,
        v_down, nullptr, down_wb, nullptr, indices);

    (void)in_sizes; (void)n_in; (void)out_size; (void)ws_size;
}

// Round 3
// 1964.197 us; speedup vs baseline: 1.1359x; 1.0485x over previous
//
#include <hip/hip_runtime.h>
#include <hip/hip_bf16.h>
#include <cstdint>

// ---------------------------------------------------------------------------
// LlamaMlpWithLora: T=2048, H=4096, I=11008, A=8, L=1, R=16, scale=0.5
// bf16 MFMA GEMMs (128x128 tile, BK=64) + T2 LDS XOR-swizzle +
// R3: XCD-chunked, M-fastest block ordering (L2 locality; kills 10x overfetch)
// Fused LoRA epilogues (silu(gate+lora)*(up+lora), down+lora).
// ---------------------------------------------------------------------------

#define T_TOK 2048
#define H_DIM 4096
#define I_DIM 11008
#define R_LORA 16
#define MBLKS 16   // T_TOK / 128, same for all three GEMMs

typedef __bf16 bf16x8 __attribute__((ext_vector_type(8)));
typedef float f32x4 __attribute__((ext_vector_type(4)));

__device__ __forceinline__ float bf2f(unsigned short u) {
    union { unsigned int i; float f; } v;
    v.i = ((unsigned int)u) << 16;
    return v.f;
}
__device__ __forceinline__ unsigned short f2bf(float f) {
    __bf16 b = (__bf16)f;
    unsigned short u;
    __builtin_memcpy(&u, &b, 2);
    return u;
}

// ------------------------------ f32 -> bf16 convert ------------------------
__global__ __launch_bounds__(256) void cvt_f32_to_bf16(
    const float* __restrict__ src, unsigned short* __restrict__ dst, long long n8)
{
    long long i = (long long)blockIdx.x * blockDim.x + threadIdx.x;
    long long stride = (long long)gridDim.x * blockDim.x;
    for (; i < n8; i += stride) {
        const float4* s = reinterpret_cast<const float4*>(src + i * 8);
        float4 a = s[0];
        float4 b = s[1];
        uint4 o;
        o.x = (unsigned)f2bf(a.x) | ((unsigned)f2bf(a.y) << 16);
        o.y = (unsigned)f2bf(a.z) | ((unsigned)f2bf(a.w) << 16);
        o.z = (unsigned)f2bf(b.x) | ((unsigned)f2bf(b.y) << 16);
        o.w = (unsigned)f2bf(b.z) | ((unsigned)f2bf(b.w) << 16);
        *reinterpret_cast<uint4*>(dst + i * 8) = o;
    }
}

// ------------------------------ LoRA v = x . waT ---------------------------
__global__ __launch_bounds__(256) void lora_v_gu(
    const float* __restrict__ x, const float* __restrict__ gwa,
    const float* __restrict__ uwa, const int* __restrict__ idx,
    float* __restrict__ vg, float* __restrict__ vu)
{
    const int t = blockIdx.x;
    const int a = idx[t];
    const int wid = threadIdx.x >> 6;
    const int lane = threadIdx.x & 63;
    const float* xr = x + (size_t)t * H_DIM;
    const float* wa = (wid < 2 ? gwa : uwa) + (size_t)a * R_LORA * H_DIM;
    float* vout = (wid < 2 ? vg : vu) + t * R_LORA;
    const int r0 = (wid & 1) * 8;
    for (int r = r0; r < r0 + 8; ++r) {
        const float* w = wa + (size_t)r * H_DIM;
        float s = 0.f;
        for (int h = lane; h < H_DIM; h += 64) s += xr[h] * w[h];
        #pragma unroll
        for (int off = 32; off > 0; off >>= 1) s += __shfl_down(s, off);
        if (lane == 0) vout[r] = s;
    }
}

__global__ __launch_bounds__(256) void lora_v_down_k(
    const unsigned short* __restrict__ tmat, const float* __restrict__ dwa,
    const int* __restrict__ idx, float* __restrict__ vd)
{
    const int tok = blockIdx.x;
    const int a = idx[tok];
    const int wid = threadIdx.x >> 6;
    const int lane = threadIdx.x & 63;
    const unsigned short* tr = tmat + (size_t)tok * I_DIM;
    const float* wa = dwa + (size_t)a * R_LORA * I_DIM;
    #pragma unroll
    for (int rr = 0; rr < 4; ++rr) {
        const int r = wid * 4 + rr;
        const float* w = wa + (size_t)r * I_DIM;
        float s = 0.f;
        for (int h = lane; h < I_DIM; h += 64) s += bf2f(tr[h]) * w[h];
        #pragma unroll
        for (int off = 32; off > 0; off >>= 1) s += __shfl_down(s, off);
        if (lane == 0) vd[tok * R_LORA + r] = s;
    }
}

// ------------------------------ GEMM C = A * B^T ---------------------------
__device__ __forceinline__ void gload_lds16(const void* g, void* l) {
    __builtin_amdgcn_global_load_lds(
        (const __attribute__((address_space(1))) void*)g,
        (__attribute__((address_space(3))) void*)l,
        16, 0, 0);
}

template <int MODE>
__global__ __launch_bounds__(256) void gemm_bt(
    const unsigned short* __restrict__ A, const unsigned short* __restrict__ B,
    int M, int N, int K,
    unsigned short* __restrict__ out_bf16,
    const unsigned short* __restrict__ gate_in,
    float* __restrict__ out_f32,
    const float* __restrict__ v1, const float* __restrict__ v2,
    const float* __restrict__ wb1, const float* __restrict__ wb2,
    const int* __restrict__ idx)
{
    (void)M;
    __shared__ __align__(16) unsigned short As[128][64];
    __shared__ __align__(16) unsigned short Bs[128][64];

    const int tid = threadIdx.x;
    const int lane = tid & 63;
    const int wid = tid >> 6;
    const int wr = wid >> 1;
    const int wc = wid & 1;
    const int fr = lane & 15;       // fragment row within 16
    const int hi = lane >> 4;       // 0..3 -> logical 16B slot offset
    const int fsw = fr & 7;         // row-derived swizzle key

    // XCD-chunked, M-fastest block ordering. nwg % 8 == 0 for all grids here.
    const int nwg = gridDim.x;
    const int swz = (blockIdx.x & 7) * (nwg >> 3) + (blockIdx.x >> 3);
    const int bm0 = (swz & (MBLKS - 1)) * 128;   // M varies fastest -> B-panel reuse
    const int bn0 = (swz / MBLKS) * 128;

    // Staging: linear LDS dest (global_load_lds rule) + inverse-swizzled
    // per-lane GLOBAL source column (same XOR involution as the ds_read).
    const int srow = tid >> 3;
    const int sslot = tid & 7;
    const int gcol = ((sslot ^ (srow & 7)) * 8);
    const unsigned short* gA = A + (size_t)(bm0 + srow) * K + gcol;
    const unsigned short* gB = B + (size_t)(bn0 + srow) * K + gcol;
    unsigned short* lA = &As[srow][sslot * 8];
    unsigned short* lB = &Bs[srow][sslot * 8];

    f32x4 acc[4][4] = {};

    for (int kt = 0; kt < K; kt += 64) {
        #pragma unroll
        for (int it = 0; it < 4; ++it) {
            gload_lds16(gA + (size_t)(it * 32) * K + kt, lA + it * 32 * 64);
            gload_lds16(gB + (size_t)(it * 32) * K + kt, lB + it * 32 * 64);
        }
        __syncthreads();
        #pragma unroll
        for (int kk = 0; kk < 64; kk += 32) {
            const int ls = kk >> 3;   // logical slot base (0 or 4)
            bf16x8 af[4];
            bf16x8 bfv[4];
            #pragma unroll
            for (int m = 0; m < 4; ++m)
                af[m] = *reinterpret_cast<const bf16x8*>(
                    &As[wr * 64 + m * 16 + fr][((ls + hi) ^ fsw) * 8]);
            #pragma unroll
            for (int n = 0; n < 4; ++n)
                bfv[n] = *reinterpret_cast<const bf16x8*>(
                    &Bs[wc * 64 + n * 16 + fr][((ls + hi) ^ fsw) * 8]);
            #pragma unroll
            for (int m = 0; m < 4; ++m)
                #pragma unroll
                for (int n = 0; n < 4; ++n)
                    acc[m][n] = __builtin_amdgcn_mfma_f32_16x16x32_bf16(
                        af[m], bfv[n], acc[m][n], 0, 0, 0);
        }
        __syncthreads();
    }

    // C/D layout (verified m89/m91): col = lane&15, row = (lane>>4)*4 + reg
    const int orow0 = bm0 + wr * 64 + (lane >> 4) * 4;
    const int ocol0 = bn0 + wc * 64 + fr;

    if constexpr (MODE == 0) {
        #pragma unroll
        for (int m = 0; m < 4; ++m)
            #pragma unroll
            for (int j = 0; j < 4; ++j) {
                const int row = orow0 + m * 16 + j;
                #pragma unroll
                for (int n = 0; n < 4; ++n)
                    out_bf16[(size_t)row * N + ocol0 + n * 16] = f2bf(acc[m][n][j]);
            }
    } else if constexpr (MODE == 1) {
        #pragma unroll
        for (int m = 0; m < 4; ++m) {
            #pragma unroll
            for (int j = 0; j < 4; ++j) {
                const int row = orow0 + m * 16 + j;
                const int a = idx[row];
                const float* vg = v1 + row * R_LORA;
                const float* vu = v2 + row * R_LORA;
                #pragma unroll
                for (int n = 0; n < 4; ++n) {
                    const int col = ocol0 + n * 16;
                    const float* wg = wb1 + ((size_t)a * N + col) * R_LORA;
                    const float* wu = wb2 + ((size_t)a * N + col) * R_LORA;
                    float lg = 0.f, lu = 0.f;
                    #pragma unroll
                    for (int r = 0; r < R_LORA; ++r) {
                        lg += vg[r] * wg[r];
                        lu += vu[r] * wu[r];
                    }
                    float g = bf2f(gate_in[(size_t)row * N + col]) + 0.5f * lg;
                    float u = acc[m][n][j] + 0.5f * lu;
                    float sg = g / (1.f + __expf(-g));
                    out_bf16[(size_t)row * N + col] = f2bf(sg * u);
                }
            }
        }
    } else {
        #pragma unroll
        for (int m = 0; m < 4; ++m) {
            #pragma unroll
            for (int j = 0; j < 4; ++j) {
                const int row = orow0 + m * 16 + j;
                const int a = idx[row];
                const float* vd = v1 + row * R_LORA;
                #pragma unroll
                for (int n = 0; n < 4; ++n) {
                    const int col = ocol0 + n * 16;
                    const float* wd = wb1 + ((size_t)a * N + col) * R_LORA;
                    float ld = 0.f;
                    #pragma unroll
                    for (int r = 0; r < R_LORA; ++r) ld += vd[r] * wd[r];
                    out_f32[(size_t)row * N + col] = acc[m][n][j] + 0.5f * ld;
                }
            }
        }
    }
}

// ---------------------------------------------------------------------------
extern "C" void kernel_launch(void* const* d_in, const int* in_sizes, int n_in,
                              void* d_out, int out_size, void* d_ws, size_t ws_size,
                              hipStream_t stream)
{
    const float* x       = (const float*)d_in[0];
    const float* gate_w  = (const float*)d_in[1];
    const float* up_w    = (const float*)d_in[2];
    const float* down_w  = (const float*)d_in[3];
    const float* gate_wa = (const float*)d_in[4];
    const float* gate_wb = (const float*)d_in[5];
    const float* up_wa   = (const float*)d_in[6];
    const float* up_wb   = (const float*)d_in[7];
    const float* down_wa = (const float*)d_in[8];
    const float* down_wb = (const float*)d_in[9];
    const int*   indices = (const int*)d_in[10];
    float* out = (float*)d_out;

    char* ws = (char*)d_ws;
    size_t off = 0;
    auto alloc = [&](size_t bytes) {
        char* p = ws + off;
        off += (bytes + 255) & ~(size_t)255;
        return p;
    };
    const size_t W_BYTES = (size_t)I_DIM * H_DIM * 2;          // 90.2 MB (reused slot)
    unsigned short* w1    = (unsigned short*)alloc(W_BYTES);
    unsigned short* xb    = (unsigned short*)alloc((size_t)T_TOK * H_DIM * 2);
    unsigned short* gateB = (unsigned short*)alloc((size_t)T_TOK * I_DIM * 2);
    unsigned short* tB    = (unsigned short*)alloc((size_t)T_TOK * I_DIM * 2);
    float* v_gate = (float*)alloc((size_t)T_TOK * R_LORA * 4);
    float* v_up   = (float*)alloc((size_t)T_TOK * R_LORA * 4);
    float* v_down = (float*)alloc((size_t)T_TOK * R_LORA * 4);

    const long long n8_x = (long long)T_TOK * H_DIM / 8;
    const long long n8_w = (long long)I_DIM * H_DIM / 8;

    cvt_f32_to_bf16<<<2048, 256, 0, stream>>>(x, xb, n8_x);
    cvt_f32_to_bf16<<<4096, 256, 0, stream>>>(gate_w, w1, n8_w);
    lora_v_gu<<<T_TOK, 256, 0, stream>>>(x, gate_wa, up_wa, indices, v_gate, v_up);

    // gate = x @ gate_w^T  (raw, bf16); 1-D grid, M-fastest + XCD chunking
    gemm_bt<0><<<MBLKS * (I_DIM / 128), 256, 0, stream>>>(
        xb, w1, T_TOK, I_DIM, H_DIM, gateB, nullptr, nullptr,
        nullptr, nullptr, nullptr, nullptr, indices);

    // up_w -> bf16 (reuse slot), fused up-GEMM -> t
    cvt_f32_to_bf16<<<4096, 256, 0, stream>>>(up_w, w1, n8_w);
    gemm_bt<1><<<MBLKS * (I_DIM / 128), 256, 0, stream>>>(
        xb, w1, T_TOK, I_DIM, H_DIM, tB, gateB, nullptr,
        v_gate, v_up, gate_wb, up_wb, indices);

    // down_w -> bf16 (reuse slot), v_down from t, down-GEMM -> out (fp32)
    cvt_f32_to_bf16<<<4096, 256, 0, stream>>>(down_w, w1, n8_w);
    lora_v_down_k<<<T_TOK, 256, 0, stream>>>(tB, down_wa, indices, v_down);
    gemm_bt<2><<<MBLKS * (H_DIM / 128), 256, 0, stream>>>(
        tB, w1, T_TOK, H_DIM, I_DIM, nullptr, nullptr, out,
        v_down, nullptr, down_wb, nullptr, indices);

    (void)in_sizes; (void)n_in; (void)out_size; (void)ws_size;
}

// Round 4
// 1775.227 us; speedup vs baseline: 1.2568x; 1.1064x over previous
//
#include <hip/hip_runtime.h>
#include <hip/hip_bf16.h>
#include <cstdint>

// ---------------------------------------------------------------------------
// LlamaMlpWithLora: T=2048, H=4096, I=11008, A=8, L=1, R=16, scale=0.5
// R4: 256x256 8-phase GEMM (T2 swizzle + T3/T4 counted vmcnt + T5 setprio).
//   8 waves (2Mx4N), per-wave 128x64, BK=64, LDS 128KB dbuf.
//   Stage units (8KB = 64rows x 64cols): per K-tile t+1 staged at
//   p0:{B0,B1,B2} p1:{B3,A0,A2} p2:{A1,A3}; waits vmcnt(6)@p1, vmcnt(2)@p3.
// Fused LoRA epilogues (silu(gate+lora)*(up+lora), down+lora).
// ---------------------------------------------------------------------------

#define T_TOK 2048
#define H_DIM 4096
#define I_DIM 11008
#define R_LORA 16

typedef __bf16 bf16x8 __attribute__((ext_vector_type(8)));
typedef float f32x4 __attribute__((ext_vector_type(4)));

__device__ __forceinline__ float bf2f(unsigned short u) {
    union { unsigned int i; float f; } v;
    v.i = ((unsigned int)u) << 16;
    return v.f;
}
__device__ __forceinline__ unsigned short f2bf(float f) {
    __bf16 b = (__bf16)f;
    unsigned short u;
    __builtin_memcpy(&u, &b, 2);
    return u;
}

// ------------------------------ f32 -> bf16 convert ------------------------
__global__ __launch_bounds__(256) void cvt_f32_to_bf16(
    const float* __restrict__ src, unsigned short* __restrict__ dst, long long n8)
{
    long long i = (long long)blockIdx.x * blockDim.x + threadIdx.x;
    long long stride = (long long)gridDim.x * blockDim.x;
    for (; i < n8; i += stride) {
        const float4* s = reinterpret_cast<const float4*>(src + i * 8);
        float4 a = s[0];
        float4 b = s[1];
        uint4 o;
        o.x = (unsigned)f2bf(a.x) | ((unsigned)f2bf(a.y) << 16);
        o.y = (unsigned)f2bf(a.z) | ((unsigned)f2bf(a.w) << 16);
        o.z = (unsigned)f2bf(b.x) | ((unsigned)f2bf(b.y) << 16);
        o.w = (unsigned)f2bf(b.z) | ((unsigned)f2bf(b.w) << 16);
        *reinterpret_cast<uint4*>(dst + i * 8) = o;
    }
}

// ------------------------------ LoRA v = x . waT ---------------------------
__global__ __launch_bounds__(256) void lora_v_gu(
    const float* __restrict__ x, const float* __restrict__ gwa,
    const float* __restrict__ uwa, const int* __restrict__ idx,
    float* __restrict__ vg, float* __restrict__ vu)
{
    const int t = blockIdx.x;
    const int a = idx[t];
    const int wid = threadIdx.x >> 6;
    const int lane = threadIdx.x & 63;
    const float* xr = x + (size_t)t * H_DIM;
    const float* wa = (wid < 2 ? gwa : uwa) + (size_t)a * R_LORA * H_DIM;
    float* vout = (wid < 2 ? vg : vu) + t * R_LORA;
    const int r0 = (wid & 1) * 8;
    for (int r = r0; r < r0 + 8; ++r) {
        const float* w = wa + (size_t)r * H_DIM;
        float s = 0.f;
        for (int h = lane; h < H_DIM; h += 64) s += xr[h] * w[h];
        #pragma unroll
        for (int off = 32; off > 0; off >>= 1) s += __shfl_down(s, off);
        if (lane == 0) vout[r] = s;
    }
}

__global__ __launch_bounds__(256) void lora_v_down_k(
    const unsigned short* __restrict__ tmat, const float* __restrict__ dwa,
    const int* __restrict__ idx, float* __restrict__ vd)
{
    const int tok = blockIdx.x;
    const int a = idx[tok];
    const int wid = threadIdx.x >> 6;
    const int lane = threadIdx.x & 63;
    const unsigned short* tr = tmat + (size_t)tok * I_DIM;
    const float* wa = dwa + (size_t)a * R_LORA * I_DIM;
    #pragma unroll
    for (int rr = 0; rr < 4; ++rr) {
        const int r = wid * 4 + rr;
        const float* w = wa + (size_t)r * I_DIM;
        float s = 0.f;
        for (int h = lane; h < I_DIM; h += 64) s += bf2f(tr[h]) * w[h];
        #pragma unroll
        for (int off = 32; off > 0; off >>= 1) s += __shfl_down(s, off);
        if (lane == 0) vd[tok * R_LORA + r] = s;
    }
}

// ------------------------------ GEMM C = A * B^T ---------------------------
__device__ __forceinline__ void gload_lds16(const void* g, void* l) {
    __builtin_amdgcn_global_load_lds(
        (const __attribute__((address_space(1))) void*)g,
        (__attribute__((address_space(3))) void*)l,
        16, 0, 0);
}

// One 8-phase phase: 12 ds_reads, stage issues, optional vmcnt, barrier,
// lgkmcnt(0)+sched_barrier (rule #18), setprio-wrapped 16 MFMA, barrier.
#define PHASE(QM, QN, STAGES, WAITS)                                          \
    do {                                                                      \
        bf16x8 a_[4][2];                                                      \
        bf16x8 b_[2][2];                                                      \
        _Pragma("unroll")                                                     \
        for (int mm = 0; mm < 4; ++mm) {                                      \
            _Pragma("unroll")                                                 \
            for (int kk = 0; kk < 2; ++kk)                                    \
                a_[mm][kk] = *reinterpret_cast<const bf16x8*>(                \
                    &lds[cur][0][wr * 128 + (QM) * 64 + mm * 16 + fr]         \
                        [((kk * 4 + hi) ^ fsw) * 8]);                         \
        }                                                                     \
        _Pragma("unroll")                                                     \
        for (int nn = 0; nn < 2; ++nn) {                                      \
            _Pragma("unroll")                                                 \
            for (int kk = 0; kk < 2; ++kk)                                    \
                b_[nn][kk] = *reinterpret_cast<const bf16x8*>(                \
                    &lds[cur][1][wc * 64 + (QN) * 32 + nn * 16 + fr]          \
                        [((kk * 4 + hi) ^ fsw) * 8]);                         \
        }                                                                     \
        STAGES;                                                               \
        WAITS;                                                                \
        __builtin_amdgcn_s_barrier();                                         \
        asm volatile("s_waitcnt lgkmcnt(0)" ::: "memory");                    \
        __builtin_amdgcn_sched_barrier(0);                                    \
        __builtin_amdgcn_s_setprio(1);                                        \
        _Pragma("unroll")                                                     \
        for (int mm = 0; mm < 4; ++mm) {                                      \
            _Pragma("unroll")                                                 \
            for (int nn = 0; nn < 2; ++nn) {                                  \
                _Pragma("unroll")                                             \
                for (int kk = 0; kk < 2; ++kk)                                \
                    acc[(QM) * 4 + mm][(QN) * 2 + nn] =                       \
                        __builtin_amdgcn_mfma_f32_16x16x32_bf16(              \
                            a_[mm][kk], b_[nn][kk],                           \
                            acc[(QM) * 4 + mm][(QN) * 2 + nn], 0, 0, 0);      \
            }                                                                 \
        }                                                                     \
        __builtin_amdgcn_s_setprio(0);                                        \
        __builtin_amdgcn_s_barrier();                                         \
        asm volatile("" ::: "memory");                                        \
    } while (0)

template <int MODE>
__global__ __launch_bounds__(512, 2) void gemm_bt(
    const unsigned short* __restrict__ A, const unsigned short* __restrict__ B,
    int N, int K, int ntiles,
    unsigned short* __restrict__ out_bf16,
    const unsigned short* __restrict__ gate_in,
    float* __restrict__ out_f32,
    const float* __restrict__ v1, const float* __restrict__ v2,
    const float* __restrict__ wb1, const float* __restrict__ wb2,
    const int* __restrict__ idx)
{
    // [buf][mat(0=A,1=B)][row][col] bf16, 128 KiB total
    __shared__ __align__(16) unsigned short lds[2][2][256][64];

    const int tid = threadIdx.x;
    const int lane = tid & 63;
    const int wid = tid >> 6;          // 0..7
    const int wr = wid >> 2;           // 0..1  (M half)
    const int wc = wid & 3;            // 0..3  (N quarter)
    const int fr = lane & 15;
    const int hi = lane >> 4;          // 0..3
    const int fsw = fr & 7;            // swizzle key (= row&7 for frag rows)

    // XCD-chunked, M-fastest ordering; nwg % 8 == 0, M-blocks = 8.
    const int nwg = gridDim.x;
    const int swz = (blockIdx.x & 7) * (nwg >> 3) + (blockIdx.x >> 3);
    const int bm0 = (swz & 7) * 256;
    const int bn0 = (swz >> 3) * 256;

    // Staging: 8KB unit = 64 rows x 64 cols; thread covers row tid>>3,
    // slot tid&7. Linear LDS dest + inverse-swizzled global source column.
    const int srow = tid >> 3;         // 0..63
    const int sslot = tid & 7;
    const int gcol = (sslot ^ (srow & 7)) * 8;
    const unsigned short* Ag = A + (size_t)(bm0 + srow) * K + gcol;
    const unsigned short* Bg = B + (size_t)(bn0 + srow) * K + gcol;

    f32x4 acc[8][4] = {};

    int cur = 0;

    // helpers -------------------------------------------------------------
    auto stA = [&](int buf, int qi, int kt) {
        gload_lds16(Ag + (size_t)(qi * 64) * K + kt,
                    &lds[buf][0][qi * 64 + srow][sslot * 8]);
    };
    auto stB = [&](int buf, int qi, int kt) {
        gload_lds16(Bg + (size_t)(qi * 64) * K + kt,
                    &lds[buf][1][qi * 64 + srow][sslot * 8]);
    };

    // prologue: stage K-tile 0 fully into buf 0, drain, sync
    #pragma unroll
    for (int q = 0; q < 4; ++q) stB(0, q, 0);
    #pragma unroll
    for (int q = 0; q < 4; ++q) stA(0, q, 0);
    asm volatile("s_waitcnt vmcnt(0)" ::: "memory");
    __builtin_amdgcn_s_barrier();
    asm volatile("" ::: "memory");

    for (int t = 0; t < ntiles; ++t) {
        const int nxt = cur ^ 1;
        const bool last = (t == ntiles - 1);
        const int ktn = (t + 1) * 64;

        // P0 (qm=0,qn=0): stage B0,B1,B2 of t+1
        PHASE(0, 0,
              { if (!last) { stB(nxt, 0, ktn); stB(nxt, 1, ktn); stB(nxt, 2, ktn); } },
              {});
        // P1 (qm=0,qn=1): stage B3,A0,A2; wait vmcnt(6) (vmcnt(0) on last tile)
        PHASE(0, 1,
              { if (!last) { stB(nxt, 3, ktn); stA(nxt, 0, ktn); stA(nxt, 2, ktn); } },
              { if (last) asm volatile("s_waitcnt vmcnt(0)" ::: "memory");
                else      asm volatile("s_waitcnt vmcnt(6)" ::: "memory"); });
        // P2 (qm=1,qn=0): stage A1,A3
        PHASE(1, 0,
              { if (!last) { stA(nxt, 1, ktn); stA(nxt, 3, ktn); } },
              {});
        // P3 (qm=1,qn=1): wait vmcnt(2)
        PHASE(1, 1, {},
              { asm volatile("s_waitcnt vmcnt(2)" ::: "memory"); });

        cur = nxt;
    }

    // Epilogue. C/D layout: col = lane&15, row = (lane>>4)*4 + reg (m89/m91).
    const int orow0 = bm0 + wr * 128 + hi * 4;
    const int ocol0 = bn0 + wc * 64 + fr;

    if constexpr (MODE == 0) {
        #pragma unroll
        for (int m = 0; m < 8; ++m)
            #pragma unroll
            for (int j = 0; j < 4; ++j) {
                const int row = orow0 + m * 16 + j;
                #pragma unroll
                for (int n = 0; n < 4; ++n)
                    out_bf16[(size_t)row * N + ocol0 + n * 16] = f2bf(acc[m][n][j]);
            }
    } else if constexpr (MODE == 1) {
        #pragma unroll
        for (int m = 0; m < 8; ++m) {
            #pragma unroll
            for (int j = 0; j < 4; ++j) {
                const int row = orow0 + m * 16 + j;
                const int a = idx[row];
                const float* vg = v1 + row * R_LORA;
                const float* vu = v2 + row * R_LORA;
                #pragma unroll
                for (int n = 0; n < 4; ++n) {
                    const int col = ocol0 + n * 16;
                    const float* wg = wb1 + ((size_t)a * N + col) * R_LORA;
                    const float* wu = wb2 + ((size_t)a * N + col) * R_LORA;
                    float lg = 0.f, lu = 0.f;
                    #pragma unroll
                    for (int r = 0; r < R_LORA; ++r) {
                        lg += vg[r] * wg[r];
                        lu += vu[r] * wu[r];
                    }
                    float g = bf2f(gate_in[(size_t)row * N + col]) + 0.5f * lg;
                    float u = acc[m][n][j] + 0.5f * lu;
                    float sg = g / (1.f + __expf(-g));
                    out_bf16[(size_t)row * N + col] = f2bf(sg * u);
                }
            }
        }
    } else {
        #pragma unroll
        for (int m = 0; m < 8; ++m) {
            #pragma unroll
            for (int j = 0; j < 4; ++j) {
                const int row = orow0 + m * 16 + j;
                const int a = idx[row];
                const float* vd = v1 + row * R_LORA;
                #pragma unroll
                for (int n = 0; n < 4; ++n) {
                    const int col = ocol0 + n * 16;
                    const float* wd = wb1 + ((size_t)a * N + col) * R_LORA;
                    float ld = 0.f;
                    #pragma unroll
                    for (int r = 0; r < R_LORA; ++r) ld += vd[r] * wd[r];
                    out_f32[(size_t)row * N + col] = acc[m][n][j] + 0.5f * ld;
                }
            }
        }
    }
}

// ---------------------------------------------------------------------------
extern "C" void kernel_launch(void* const* d_in, const int* in_sizes, int n_in,
                              void* d_out, int out_size, void* d_ws, size_t ws_size,
                              hipStream_t stream)
{
    const float* x       = (const float*)d_in[0];
    const float* gate_w  = (const float*)d_in[1];
    const float* up_w    = (const float*)d_in[2];
    const float* down_w  = (const float*)d_in[3];
    const float* gate_wa = (const float*)d_in[4];
    const float* gate_wb = (const float*)d_in[5];
    const float* up_wa   = (const float*)d_in[6];
    const float* up_wb   = (const float*)d_in[7];
    const float* down_wa = (const float*)d_in[8];
    const float* down_wb = (const float*)d_in[9];
    const int*   indices = (const int*)d_in[10];
    float* out = (float*)d_out;

    char* ws = (char*)d_ws;
    size_t off = 0;
    auto alloc = [&](size_t bytes) {
        char* p = ws + off;
        off += (bytes + 255) & ~(size_t)255;
        return p;
    };
    const size_t W_BYTES = (size_t)I_DIM * H_DIM * 2;          // 90.2 MB (reused slot)
    unsigned short* w1    = (unsigned short*)alloc(W_BYTES);
    unsigned short* xb    = (unsigned short*)alloc((size_t)T_TOK * H_DIM * 2);
    unsigned short* gateB = (unsigned short*)alloc((size_t)T_TOK * I_DIM * 2);
    unsigned short* tB    = (unsigned short*)alloc((size_t)T_TOK * I_DIM * 2);
    float* v_gate = (float*)alloc((size_t)T_TOK * R_LORA * 4);
    float* v_up   = (float*)alloc((size_t)T_TOK * R_LORA * 4);
    float* v_down = (float*)alloc((size_t)T_TOK * R_LORA * 4);

    const long long n8_x = (long long)T_TOK * H_DIM / 8;
    const long long n8_w = (long long)I_DIM * H_DIM / 8;

    cvt_f32_to_bf16<<<2048, 256, 0, stream>>>(x, xb, n8_x);
    cvt_f32_to_bf16<<<4096, 256, 0, stream>>>(gate_w, w1, n8_w);
    lora_v_gu<<<T_TOK, 256, 0, stream>>>(x, gate_wa, up_wa, indices, v_gate, v_up);

    // gate = x @ gate_w^T (raw bf16). grid: 8 M-blocks x 43 N-blocks = 344
    gemm_bt<0><<<8 * (I_DIM / 256), 512, 0, stream>>>(
        xb, w1, I_DIM, H_DIM, H_DIM / 64, gateB, nullptr, nullptr,
        nullptr, nullptr, nullptr, nullptr, indices);

    // up_w -> bf16 (reuse slot), fused up-GEMM -> t
    cvt_f32_to_bf16<<<4096, 256, 0, stream>>>(up_w, w1, n8_w);
    gemm_bt<1><<<8 * (I_DIM / 256), 512, 0, stream>>>(
        xb, w1, I_DIM, H_DIM, H_DIM / 64, tB, gateB, nullptr,
        v_gate, v_up, gate_wb, up_wb, indices);

    // down_w -> bf16 (reuse slot), v_down from t, down-GEMM -> out (fp32)
    cvt_f32_to_bf16<<<4096, 256, 0, stream>>>(down_w, w1, n8_w);
    lora_v_down_k<<<T_TOK, 256, 0, stream>>>(tB, down_wa, indices, v_down);
    gemm_bt<2><<<8 * (H_DIM / 256), 512, 0, stream>>>(
        tB, w1, H_DIM, I_DIM, I_DIM / 64, nullptr, nullptr, out,
        v_down, nullptr, down_wb, nullptr, indices);

    (void)in_sizes; (void)n_in; (void)out_size; (void)ws_size;
}

// Round 5
// 1230.271 us; speedup vs baseline: 1.8136x; 1.4430x over previous
//
#include <hip/hip_runtime.h>
#include <hip/hip_bf16.h>
#include <cstdint>

// ---------------------------------------------------------------------------
// LlamaMlpWithLora: T=2048, H=4096, I=11008, A=8, R=16, scale=0.5
// R5: LoRA folded into GEMM K (augmented operands), gate+up fused,
//     m97-class 128x128/BK=64 single-buffer GEMMs, 3 blocks/CU,
//     A-stationary N-fastest XCD chunking.
//   xa   [T][4352]  = [x | 0.5*v_g (adapter slot) | 0.5*v_u]
//   Wg^  [I][4352]  = [gate_w | wb_g cols | 0]
//   Wu^  [I][4352]  = [up_w   | 0 | wb_u cols]
//   t^   [T][11136] = [silu(gate)*up | 0.5*v_d slots]
//   Wd^  [H][11136] = [down_w | wb_d cols]
// ---------------------------------------------------------------------------

#define T_TOK 2048
#define H_DIM 4096
#define I_DIM 11008
#define NA 8
#define R_LORA 16
#define KA1 4352    // H + 128(gate) + 128(up)
#define KA2 11136   // I + 128(down)

typedef __bf16 bf16x8 __attribute__((ext_vector_type(8)));
typedef float f32x4 __attribute__((ext_vector_type(4)));

__device__ __forceinline__ float bf2f(unsigned short u) {
    union { unsigned int i; float f; } v;
    v.i = ((unsigned int)u) << 16;
    return v.f;
}
__device__ __forceinline__ unsigned short f2bf(float f) {
    __bf16 b = (__bf16)f;
    unsigned short u;
    __builtin_memcpy(&u, &b, 2);
    return u;
}
__device__ __forceinline__ void cvt8(const float* s, unsigned short* d) {
    float4 a = reinterpret_cast<const float4*>(s)[0];
    float4 b = reinterpret_cast<const float4*>(s)[1];
    uint4 o;
    o.x = (unsigned)f2bf(a.x) | ((unsigned)f2bf(a.y) << 16);
    o.y = (unsigned)f2bf(a.z) | ((unsigned)f2bf(a.w) << 16);
    o.z = (unsigned)f2bf(b.x) | ((unsigned)f2bf(b.y) << 16);
    o.w = (unsigned)f2bf(b.z) | ((unsigned)f2bf(b.w) << 16);
    *reinterpret_cast<uint4*>(d) = o;
}
__device__ __forceinline__ void gload_lds16(const void* g, void* l) {
    __builtin_amdgcn_global_load_lds(
        (const __attribute__((address_space(1))) void*)g,
        (__attribute__((address_space(3))) void*)l,
        16, 0, 0);
}

// ---------------- builders -------------------------------------------------
// One weight row -> bf16 + lora-B aug columns (+ optional zero range).
__global__ __launch_bounds__(256) void build_w_aug(
    const float* __restrict__ w, const float* __restrict__ wb,
    unsigned short* __restrict__ dst,
    int Nrows, int Ksrc, int Kdst, int self_off, int zero_off)
{
    const int c = blockIdx.x;
    const int tid = threadIdx.x;
    const float* src = w + (size_t)c * Ksrc;
    unsigned short* d = dst + (size_t)c * Kdst;
    for (int k = tid * 8; k < Ksrc; k += 256 * 8) cvt8(src + k, d + k);
    if (tid < 128) {
        const int a = tid >> 4, r = tid & 15;
        const float v = wb[(((size_t)a * Nrows) + c) * R_LORA + r];
        d[self_off + tid] = f2bf(v);
        if (zero_off >= 0) d[zero_off + tid] = 0;  // +0.0 bf16
    }
}

// xa row: bf16(x) + 256 aug cols (0.5*v_g at token's adapter slot, 0.5*v_u)
__global__ __launch_bounds__(256) void build_xa(
    const float* __restrict__ x, const float* __restrict__ vg,
    const float* __restrict__ vu, const int* __restrict__ idx,
    unsigned short* __restrict__ dst)
{
    const int t = blockIdx.x;
    const int tid = threadIdx.x;
    const float* src = x + (size_t)t * H_DIM;
    unsigned short* d = dst + (size_t)t * KA1;
    for (int k = tid * 8; k < H_DIM; k += 2048) cvt8(src + k, d + k);
    const int a_t = idx[t];
    const int grp = tid >> 7;          // 0=gate cols, 1=up cols
    const int sub = tid & 127;
    const int a = sub >> 4, r = sub & 15;
    float v = 0.f;
    if (a == a_t) v = 0.5f * (grp ? vu : vg)[t * R_LORA + r];
    d[H_DIM + tid] = f2bf(v);
}

__global__ __launch_bounds__(128) void fill_ta(
    const float* __restrict__ vd, const int* __restrict__ idx,
    unsigned short* __restrict__ t_aug)
{
    const int t = blockIdx.x;
    const int tid = threadIdx.x;   // 0..127
    const int a = tid >> 4, r = tid & 15;
    float v = (a == idx[t]) ? 0.5f * vd[t * R_LORA + r] : 0.f;
    t_aug[(size_t)t * KA2 + I_DIM + tid] = f2bf(v);
}

// ---------------- LoRA v ----------------------------------------------------
__global__ __launch_bounds__(256) void lora_v_gu(
    const float* __restrict__ x, const float* __restrict__ gwa,
    const float* __restrict__ uwa, const int* __restrict__ idx,
    float* __restrict__ vg, float* __restrict__ vu)
{
    const int t = blockIdx.x;
    const int a = idx[t];
    const int wid = threadIdx.x >> 6;
    const int lane = threadIdx.x & 63;
    const float* xr = x + (size_t)t * H_DIM;
    const float* wa = (wid < 2 ? gwa : uwa) + (size_t)a * R_LORA * H_DIM;
    float* vout = (wid < 2 ? vg : vu) + t * R_LORA;
    const int r0 = (wid & 1) * 8;
    for (int r = r0; r < r0 + 8; ++r) {
        const float* w = wa + (size_t)r * H_DIM;
        float s = 0.f;
        for (int h = lane; h < H_DIM; h += 64) s += xr[h] * w[h];
        #pragma unroll
        for (int off = 32; off > 0; off >>= 1) s += __shfl_down(s, off);
        if (lane == 0) vout[r] = s;
    }
}

__global__ __launch_bounds__(256) void lora_v_down_k(
    const unsigned short* __restrict__ tmat, const float* __restrict__ dwa,
    const int* __restrict__ idx, float* __restrict__ vd)
{
    const int tok = blockIdx.x;
    const int a = idx[tok];
    const int wid = threadIdx.x >> 6;
    const int lane = threadIdx.x & 63;
    const unsigned short* tr = tmat + (size_t)tok * KA2;
    const float* wa = dwa + (size_t)a * R_LORA * I_DIM;
    #pragma unroll
    for (int rr = 0; rr < 4; ++rr) {
        const int r = wid * 4 + rr;
        const float* w = wa + (size_t)r * I_DIM;
        float s = 0.f;
        for (int h = lane; h < I_DIM; h += 64) s += bf2f(tr[h]) * w[h];
        #pragma unroll
        for (int off = 32; off > 0; off >>= 1) s += __shfl_down(s, off);
        if (lane == 0) vd[tok * R_LORA + r] = s;
    }
}

// ---------------- pass 1: fused gate+up GEMM -------------------------------
// 128x128 tile, BK=64, 8 waves (2Mx4N), per-wave 64x32 per matrix.
__global__ __launch_bounds__(512) void gemm_fused_gu(
    const unsigned short* __restrict__ A,   // xa [T][KA1]
    const unsigned short* __restrict__ Bg,  // wg_aug [I][KA1]
    const unsigned short* __restrict__ Bu,  // wu_aug [I][KA1]
    unsigned short* __restrict__ Tout)      // t_aug [T][KA2]
{
    __shared__ __align__(16) unsigned short As[128][64];
    __shared__ __align__(16) unsigned short Bgs[128][64];
    __shared__ __align__(16) unsigned short Bus[128][64];

    const int tid = threadIdx.x;
    const int lane = tid & 63;
    const int wid = tid >> 6;
    const int wr = wid >> 2;           // 0..1
    const int wc = wid & 3;            // 0..3
    const int fr = lane & 15;
    const int hi = lane >> 4;
    const int fsw = fr & 7;

    // A-stationary: XCD chunk (172 blocks) = 2 bm x 86 bn, bn fastest.
    const int nwg = gridDim.x;                                   // 1376
    const int swz = (blockIdx.x & 7) * (nwg >> 3) + (blockIdx.x >> 3);
    const int bm0 = (swz / 86) * 128;
    const int bn0 = (swz % 86) * 128;

    const int srow = tid >> 3;         // 0..63
    const int sslot = tid & 7;
    const int gcol = (sslot ^ (srow & 7)) * 8;
    const unsigned short* Ag  = A  + (size_t)(bm0 + srow) * KA1 + gcol;
    const unsigned short* Bgg = Bg + (size_t)(bn0 + srow) * KA1 + gcol;
    const unsigned short* Bug = Bu + (size_t)(bn0 + srow) * KA1 + gcol;
    const size_t half = (size_t)64 * KA1;

    f32x4 accg[4][2] = {};
    f32x4 accu[4][2] = {};

    for (int kt = 0; kt < KA1; kt += 64) {
        gload_lds16(Ag + kt,         &As[srow][sslot * 8]);
        gload_lds16(Ag + half + kt,  &As[64 + srow][sslot * 8]);
        gload_lds16(Bgg + kt,        &Bgs[srow][sslot * 8]);
        gload_lds16(Bgg + half + kt, &Bgs[64 + srow][sslot * 8]);
        gload_lds16(Bug + kt,        &Bus[srow][sslot * 8]);
        gload_lds16(Bug + half + kt, &Bus[64 + srow][sslot * 8]);
        __syncthreads();
        #pragma unroll
        for (int kk = 0; kk < 2; ++kk) {
            bf16x8 a_[4], bg_[2], bu_[2];
            #pragma unroll
            for (int m = 0; m < 4; ++m)
                a_[m] = *reinterpret_cast<const bf16x8*>(
                    &As[wr * 64 + m * 16 + fr][((kk * 4 + hi) ^ fsw) * 8]);
            #pragma unroll
            for (int n = 0; n < 2; ++n) {
                bg_[n] = *reinterpret_cast<const bf16x8*>(
                    &Bgs[wc * 32 + n * 16 + fr][((kk * 4 + hi) ^ fsw) * 8]);
                bu_[n] = *reinterpret_cast<const bf16x8*>(
                    &Bus[wc * 32 + n * 16 + fr][((kk * 4 + hi) ^ fsw) * 8]);
            }
            #pragma unroll
            for (int m = 0; m < 4; ++m)
                #pragma unroll
                for (int n = 0; n < 2; ++n) {
                    accg[m][n] = __builtin_amdgcn_mfma_f32_16x16x32_bf16(
                        a_[m], bg_[n], accg[m][n], 0, 0, 0);
                    accu[m][n] = __builtin_amdgcn_mfma_f32_16x16x32_bf16(
                        a_[m], bu_[n], accu[m][n], 0, 0, 0);
                }
        }
        __syncthreads();
    }

    // C/D layout: col = lane&15, row = (lane>>4)*4 + reg
    const int orow0 = bm0 + wr * 64 + hi * 4;
    const int ocol0 = bn0 + wc * 32 + fr;
    #pragma unroll
    for (int m = 0; m < 4; ++m)
        #pragma unroll
        for (int j = 0; j < 4; ++j) {
            const int row = orow0 + m * 16 + j;
            #pragma unroll
            for (int n = 0; n < 2; ++n) {
                const float g = accg[m][n][j];
                const float u = accu[m][n][j];
                const float sg = g / (1.f + __expf(-g));
                Tout[(size_t)row * KA2 + ocol0 + n * 16] = f2bf(sg * u);
            }
        }
}

// ---------------- pass 2: down GEMM -----------------------------------------
__global__ __launch_bounds__(512) void gemm_down(
    const unsigned short* __restrict__ A,   // t_aug [T][KA2]
    const unsigned short* __restrict__ B,   // wd_aug [H][KA2]
    float* __restrict__ out)                // [T][H]
{
    __shared__ __align__(16) unsigned short As[128][64];
    __shared__ __align__(16) unsigned short Bs[128][64];

    const int tid = threadIdx.x;
    const int lane = tid & 63;
    const int wid = tid >> 6;
    const int wr = wid >> 2;
    const int wc = wid & 3;
    const int fr = lane & 15;
    const int hi = lane >> 4;
    const int fsw = fr & 7;

    const int nwg = gridDim.x;                                   // 512
    const int swz = (blockIdx.x & 7) * (nwg >> 3) + (blockIdx.x >> 3);
    const int bm0 = (swz / 32) * 128;
    const int bn0 = (swz % 32) * 128;

    const int srow = tid >> 3;
    const int sslot = tid & 7;
    const int gcol = (sslot ^ (srow & 7)) * 8;
    const unsigned short* Ag = A + (size_t)(bm0 + srow) * KA2 + gcol;
    const unsigned short* Bg = B + (size_t)(bn0 + srow) * KA2 + gcol;
    const size_t half = (size_t)64 * KA2;

    f32x4 acc[4][2] = {};

    for (int kt = 0; kt < KA2; kt += 64) {
        gload_lds16(Ag + kt,        &As[srow][sslot * 8]);
        gload_lds16(Ag + half + kt, &As[64 + srow][sslot * 8]);
        gload_lds16(Bg + kt,        &Bs[srow][sslot * 8]);
        gload_lds16(Bg + half + kt, &Bs[64 + srow][sslot * 8]);
        __syncthreads();
        #pragma unroll
        for (int kk = 0; kk < 2; ++kk) {
            bf16x8 a_[4], b_[2];
            #pragma unroll
            for (int m = 0; m < 4; ++m)
                a_[m] = *reinterpret_cast<const bf16x8*>(
                    &As[wr * 64 + m * 16 + fr][((kk * 4 + hi) ^ fsw) * 8]);
            #pragma unroll
            for (int n = 0; n < 2; ++n)
                b_[n] = *reinterpret_cast<const bf16x8*>(
                    &Bs[wc * 32 + n * 16 + fr][((kk * 4 + hi) ^ fsw) * 8]);
            #pragma unroll
            for (int m = 0; m < 4; ++m)
                #pragma unroll
                for (int n = 0; n < 2; ++n)
                    acc[m][n] = __builtin_amdgcn_mfma_f32_16x16x32_bf16(
                        a_[m], b_[n], acc[m][n], 0, 0, 0);
        }
        __syncthreads();
    }

    const int orow0 = bm0 + wr * 64 + hi * 4;
    const int ocol0 = bn0 + wc * 32 + fr;
    #pragma unroll
    for (int m = 0; m < 4; ++m)
        #pragma unroll
        for (int j = 0; j < 4; ++j) {
            const int row = orow0 + m * 16 + j;
            #pragma unroll
            for (int n = 0; n < 2; ++n)
                out[(size_t)row * H_DIM + ocol0 + n * 16] = acc[m][n][j];
        }
}

// ---------------------------------------------------------------------------
extern "C" void kernel_launch(void* const* d_in, const int* in_sizes, int n_in,
                              void* d_out, int out_size, void* d_ws, size_t ws_size,
                              hipStream_t stream)
{
    const float* x       = (const float*)d_in[0];
    const float* gate_w  = (const float*)d_in[1];
    const float* up_w    = (const float*)d_in[2];
    const float* down_w  = (const float*)d_in[3];
    const float* gate_wa = (const float*)d_in[4];
    const float* gate_wb = (const float*)d_in[5];
    const float* up_wa   = (const float*)d_in[6];
    const float* up_wb   = (const float*)d_in[7];
    const float* down_wa = (const float*)d_in[8];
    const float* down_wb = (const float*)d_in[9];
    const int*   indices = (const int*)d_in[10];
    float* out = (float*)d_out;

    char* ws = (char*)d_ws;
    size_t off = 0;
    auto alloc = [&](size_t bytes) {
        char* p = ws + off;
        off += (bytes + 255) & ~(size_t)255;
        return p;
    };
    unsigned short* xa     = (unsigned short*)alloc((size_t)T_TOK * KA1 * 2); // 17.8MB
    unsigned short* wg_aug = (unsigned short*)alloc((size_t)I_DIM * KA1 * 2); // 95.8MB
    unsigned short* wu_aug = (unsigned short*)alloc((size_t)I_DIM * KA1 * 2); // 95.8MB (wd reuses)
    unsigned short* t_aug  = (unsigned short*)alloc((size_t)T_TOK * KA2 * 2); // 45.6MB
    float* v_gate = (float*)alloc((size_t)T_TOK * R_LORA * 4);
    float* v_up   = (float*)alloc((size_t)T_TOK * R_LORA * 4);
    float* v_down = (float*)alloc((size_t)T_TOK * R_LORA * 4);
    unsigned short* wd_aug = wu_aug;   // reused after pass1 (91.2MB <= 95.8MB)

    // LoRA v for gate/up (fp32 x), then augmented operands
    lora_v_gu<<<T_TOK, 256, 0, stream>>>(x, gate_wa, up_wa, indices, v_gate, v_up);
    build_xa<<<T_TOK, 256, 0, stream>>>(x, v_gate, v_up, indices, xa);
    build_w_aug<<<I_DIM, 256, 0, stream>>>(gate_w, gate_wb, wg_aug,
                                           I_DIM, H_DIM, KA1, H_DIM, H_DIM + 128);
    build_w_aug<<<I_DIM, 256, 0, stream>>>(up_w, up_wb, wu_aug,
                                           I_DIM, H_DIM, KA1, H_DIM + 128, H_DIM);

    // fused gate+up -> t (with both LoRAs + silu*mul), grid 16x86 = 1376
    gemm_fused_gu<<<16 * 86, 512, 0, stream>>>(xa, wg_aug, wu_aug, t_aug);

    // down-LoRA v from t, fill t_aug tail, build Wd^ (reusing wu slot)
    lora_v_down_k<<<T_TOK, 256, 0, stream>>>(t_aug, down_wa, indices, v_down);
    fill_ta<<<T_TOK, 128, 0, stream>>>(v_down, indices, t_aug);
    build_w_aug<<<H_DIM, 256, 0, stream>>>(down_w, down_wb, wd_aug,
                                           H_DIM, I_DIM, KA2, I_DIM, -1);

    // down GEMM -> out (fp32), grid 16x32 = 512
    gemm_down<<<16 * 32, 512, 0, stream>>>(t_aug, wd_aug, out);

    (void)in_sizes; (void)n_in; (void)out_size; (void)ws_size;
}